// Round 1
// baseline (20.228 us; speedup 1.0000x reference)
//
#include <hip/hip_runtime.h>

#define NG 256  // number of graphs

// ---------------------------------------------------------------------------
// Kernel 1: one block of 256 threads. Computes per-graph deg, epg, and the
// exclusive prefix sums (node_off, edge_off) via LDS Hillis-Steele scan.
// Writes epg to the output tail (second tuple element) and offsets to ws.
// ---------------------------------------------------------------------------
__global__ __launch_bounds__(NG) void fc_prep_kernel(
    const int* __restrict__ num_nodes,
    int* __restrict__ d_out, int e2 /* = 2*E, start of epg tail */,
    int* __restrict__ ws) {
    __shared__ int s_n[NG];
    __shared__ int s_e[NG];

    const int t = threadIdx.x;
    const int n = num_nodes[t];
    const int deg = (n > 1) ? (n - 1) : 0;
    const int epg = n * deg;

    s_n[t] = n;
    s_e[t] = epg;
    __syncthreads();

    // Inclusive scan over 256 elements (8 steps).
    #pragma unroll
    for (int off = 1; off < NG; off <<= 1) {
        int vn = 0, ve = 0;
        if (t >= off) { vn = s_n[t - off]; ve = s_e[t - off]; }
        __syncthreads();
        s_n[t] += vn;
        s_e[t] += ve;
        __syncthreads();
    }

    const int node_off = s_n[t] - n;    // exclusive cumsum of n
    const int edge_off = s_e[t] - epg;  // exclusive cumsum of epg

    ws[t]           = node_off;
    ws[NG + t]      = edge_off;
    ws[2 * NG + t]  = deg;
    ws[3 * NG + t]  = n * deg;  // edges in this graph

    // Second output of the tuple: num_edges per graph.
    d_out[e2 + t] = epg;
}

// ---------------------------------------------------------------------------
// Kernel 2: fill edge_index. blockIdx.y = graph id; blockIdx.x strides the
// edge ranks within the graph. Each edge is one coalesced 8-byte int2 store.
// Row-major argwhere order: k = i*deg + r, j = r + (r >= i).
// ---------------------------------------------------------------------------
__global__ __launch_bounds__(256) void fc_edges_kernel(
    const int* __restrict__ ws, int* __restrict__ d_out) {
    const int g = blockIdx.y;
    const int deg = ws[2 * NG + g];
    if (deg == 0) return;
    const int node_off = ws[g];
    const int edge_off = ws[NG + g];
    const int ne = ws[3 * NG + g];

    int2* out2 = reinterpret_cast<int2*>(d_out);
    const int stride = gridDim.x * blockDim.x;
    for (int k = blockIdx.x * blockDim.x + threadIdx.x; k < ne; k += stride) {
        const unsigned int ku = (unsigned int)k;
        const unsigned int du = (unsigned int)deg;
        const int i = (int)(ku / du);
        const int r = k - i * deg;
        const int j = r + ((r >= i) ? 1 : 0);
        out2[edge_off + k] = make_int2(node_off + i, node_off + j);
    }
}

extern "C" void kernel_launch(void* const* d_in, const int* in_sizes, int n_in,
                              void* d_out, int out_size, void* d_ws, size_t ws_size,
                              hipStream_t stream) {
    const int* num_nodes = (const int*)d_in[0];  // [256], harness casts ints to int32
    int* out = (int*)d_out;                      // [2E + 256] int32
    int* ws  = (int*)d_ws;                       // >= 4*256 ints of scratch

    const int e2 = out_size - NG;  // 2*E: where the epg tail starts

    fc_prep_kernel<<<1, NG, 0, stream>>>(num_nodes, out, e2, ws);

    // Up to 255*254 = 64770 edges/graph; 32 blocks x 256 threads stride each
    // graph in <= 8 iterations. 8192 blocks total keeps all 256 CUs busy.
    dim3 grid(32, NG);
    fc_edges_kernel<<<grid, 256, 0, stream>>>(ws, out);
}

// Round 2
// 18.314 us; speedup vs baseline: 1.1045x; 1.1045x over previous
//
#include <hip/hip_runtime.h>

#define NG 256   // number of graphs
#define BPG 32   // blocks per graph (row stride)

// ---------------------------------------------------------------------------
// Fully fused: every block recomputes the per-graph exclusive cumsums with an
// 8-step LDS Hillis-Steele scan over the 256 graph sizes (input is 1 KB,
// L2-resident -> effectively free, and it removes the prep-kernel dependency).
// Then block (x, g) writes rows i = x, x+BPG, ... of graph g's adjacency:
// lane r covers column r, j = r + (r >= i), one coalesced 8B int2 store.
// No integer division anywhere on the edge path.
// ---------------------------------------------------------------------------
__global__ __launch_bounds__(256) void fc_fused_kernel(
    const int* __restrict__ num_nodes,
    int* __restrict__ d_out, int e2 /* = 2*E, start of epg tail */) {
    __shared__ int s_n[NG];
    __shared__ int s_e[NG];

    const int t = threadIdx.x;
    const int g = blockIdx.y;

    // --- per-graph sizes + inclusive scans (all blocks, redundantly) ---
    const int n0 = num_nodes[t];
    const int d0 = (n0 > 1) ? (n0 - 1) : 0;
    const int e0 = n0 * d0;
    s_n[t] = n0;
    s_e[t] = e0;
    __syncthreads();

    #pragma unroll
    for (int off = 1; off < NG; off <<= 1) {
        const int vn = (t >= off) ? s_n[t - off] : 0;
        const int ve = (t >= off) ? s_e[t - off] : 0;
        __syncthreads();
        s_n[t] += vn;
        s_e[t] += ve;
        __syncthreads();
    }

    // Second tuple output: num_edges per graph (one block writes it).
    if (blockIdx.x == 0 && g == 0) d_out[e2 + t] = e0;

    // --- this block's graph parameters (uniform; LDS broadcast reads) ---
    const int n = num_nodes[g];
    const int deg = (n > 1) ? (n - 1) : 0;
    if (deg == 0) return;
    const int node_off = s_n[g] - n;          // exclusive cumsum of n
    const int edge_off = s_e[g] - n * deg;    // exclusive cumsum of epg

    int2* out2 = reinterpret_cast<int2*>(d_out);
    const int r = t;                          // column index (dest rank)
    const bool active = (r < deg);
    const int src_base = node_off;

    for (int i = blockIdx.x; i < n; i += BPG) {
        if (active) {
            const int j = r + ((r >= i) ? 1 : 0);
            out2[edge_off + i * deg + r] = make_int2(src_base + i, src_base + j);
        }
    }
}

extern "C" void kernel_launch(void* const* d_in, const int* in_sizes, int n_in,
                              void* d_out, int out_size, void* d_ws, size_t ws_size,
                              hipStream_t stream) {
    const int* num_nodes = (const int*)d_in[0];  // [256] int32
    int* out = (int*)d_out;                      // [2E + 256] int32
    const int e2 = out_size - NG;                // 2*E: epg tail start

    dim3 grid(BPG, NG);                          // 8192 blocks
    fc_fused_kernel<<<grid, 256, 0, stream>>>(num_nodes, out, e2);
}

// Round 3
// 15.683 us; speedup vs baseline: 1.2898x; 1.1677x over previous
//
#include <hip/hip_runtime.h>

#define NG 256        // number of graphs
#define NBLK 2048     // total blocks (8 per CU), perfectly uniform work split

// ---------------------------------------------------------------------------
// One kernel. Every block:
//   1. shfl-based inclusive scan of (n, epg) over the 256 graphs (2 barriers),
//      tables in LDS with a leading 0 (s_in[0]=s_ie[0]=0).
//   2. handles a contiguous range of GLOBAL edge ranks [k0, kend) — identical
//      size for every block -> perfect balance, fully dense 512B wave-stores.
//      Per-lane graph id via one 8-step binary search, then incremental
//      advance. i = k_local/deg via v_rcp_f32 with exact two-sided fixup.
// ---------------------------------------------------------------------------
__global__ __launch_bounds__(256) void fc_flat_kernel(
    const int* __restrict__ num_nodes,
    int* __restrict__ d_out, int e2 /* = 2*E */, int W /* edges per block */) {
    __shared__ int s_in[NG + 1];  // inclusive cumsum of n, with s_in[0] = 0
    __shared__ int s_ie[NG + 1];  // inclusive cumsum of epg, with s_ie[0] = 0
    __shared__ int wsum_n[4], wsum_e[4];

    const int t = threadIdx.x;
    const int lane = t & 63;
    const int w = t >> 6;

    // --- per-graph sizes ---
    const int n0 = num_nodes[t];
    const int d0 = (n0 > 1) ? (n0 - 1) : 0;
    const int e0 = n0 * d0;

    // --- wave-level inclusive scan (no barriers) ---
    int sn = n0, se = e0;
    #pragma unroll
    for (int off = 1; off < 64; off <<= 1) {
        const int an = __shfl_up(sn, off);
        const int ae = __shfl_up(se, off);
        if (lane >= off) { sn += an; se += ae; }
    }
    if (lane == 63) { wsum_n[w] = sn; wsum_e[w] = se; }
    __syncthreads();
    #pragma unroll
    for (int w2 = 0; w2 < 3; ++w2) {
        if (w > w2) { sn += wsum_n[w2]; se += wsum_e[w2]; }
    }
    s_in[t + 1] = sn;
    s_ie[t + 1] = se;
    if (t == 0) { s_in[0] = 0; s_ie[0] = 0; }

    // Second tuple output: num_edges per graph.
    if (blockIdx.x == 0) d_out[e2 + t] = e0;
    __syncthreads();

    // --- this thread's edge range ---
    const int E = e2 >> 1;
    int k = blockIdx.x * W + t;
    const int kend = min(blockIdx.x * W + W, E);
    if (k >= kend) return;

    // Binary search: g in [lo,hi) with s_ie[g] <= k < s_ie[g+1].
    int lo = 0, hi = NG;
    #pragma unroll
    for (int step = 0; step < 8; ++step) {
        const int mid = (lo + hi) >> 1;
        if (k >= s_ie[mid]) lo = mid; else hi = mid;
    }
    int g = lo;
    int e_hi = s_ie[g + 1];

    int2* out2 = reinterpret_cast<int2*>(d_out);
    for (; k < kend; k += 256) {
        while (k >= e_hi) { ++g; e_hi = s_ie[g + 1]; }
        const int prev_n = s_in[g];
        const int deg = (s_in[g + 1] - prev_n) - 1;  // >= 1: this graph owns edges
        const int kl = k - s_ie[g];
        int i = (int)((float)kl * __builtin_amdgcn_rcpf((float)deg));
        int r = kl - i * deg;
        if (r < 0)         { --i; r += deg; }
        else if (r >= deg) { ++i; r -= deg; }
        const int j = r + ((r >= i) ? 1 : 0);
        out2[k] = make_int2(prev_n + i, prev_n + j);
    }
}

extern "C" void kernel_launch(void* const* d_in, const int* in_sizes, int n_in,
                              void* d_out, int out_size, void* d_ws, size_t ws_size,
                              hipStream_t stream) {
    const int* num_nodes = (const int*)d_in[0];  // [256] int32
    int* out = (int*)d_out;                      // [2E + 256] int32
    const int e2 = out_size - NG;                // 2*E
    const int E = e2 / 2;

    // Edges per block: uniform, rounded to 64 edges (512B) for aligned waves.
    int W = (E + NBLK - 1) / NBLK;
    W = (W + 63) & ~63;

    fc_flat_kernel<<<NBLK, 256, 0, stream>>>(num_nodes, out, e2, W);
}

// Round 5
// 14.002 us; speedup vs baseline: 1.4446x; 1.1201x over previous
//
#include <hip/hip_runtime.h>

#define NG 256        // number of graphs
#define NBLK 2048     // total blocks (8 per CU), uniform flat edge split

typedef int int4v __attribute__((ext_vector_type(4)));  // clang vector: valid
                                                        // for nontemporal store

// ---------------------------------------------------------------------------
// Flat, pairwise. Every block:
//   1. shfl-based inclusive scan of (n, epg) over 256 graphs (2 barriers).
//   2. handles contiguous global edge ranks [k0, k0+W); each thread emits
//      TWO consecutive edges per iteration as one 16B nontemporal store
//      (full 1KB/wave-store). Both epg and E are even, and all cumsum
//      boundaries are even, so an even-k pair never straddles a graph.
//      One rcp-division per pair; the second edge is a +1 wrap fixup.
// ---------------------------------------------------------------------------
__global__ __launch_bounds__(256) void fc_pair_kernel(
    const int* __restrict__ num_nodes,
    int* __restrict__ d_out, int e2 /* = 2*E */, int W /* edges/block, even */) {
    __shared__ int s_in[NG + 1];  // cumsum of n,   s_in[0] = 0
    __shared__ int s_ie[NG + 1];  // cumsum of epg, s_ie[0] = 0
    __shared__ int wsum_n[4], wsum_e[4];

    const int t = threadIdx.x;
    const int lane = t & 63;
    const int w = t >> 6;

    const int n0 = num_nodes[t];
    const int d0 = (n0 > 1) ? (n0 - 1) : 0;
    const int e0 = n0 * d0;

    int sn = n0, se = e0;
    #pragma unroll
    for (int off = 1; off < 64; off <<= 1) {
        const int an = __shfl_up(sn, off);
        const int ae = __shfl_up(se, off);
        if (lane >= off) { sn += an; se += ae; }
    }
    if (lane == 63) { wsum_n[w] = sn; wsum_e[w] = se; }
    __syncthreads();
    #pragma unroll
    for (int w2 = 0; w2 < 3; ++w2)
        if (w > w2) { sn += wsum_n[w2]; se += wsum_e[w2]; }
    s_in[t + 1] = sn;
    s_ie[t + 1] = se;
    if (t == 0) { s_in[0] = 0; s_ie[0] = 0; }

    // Second tuple output: num_edges per graph.
    if (blockIdx.x == 0) d_out[e2 + t] = e0;
    __syncthreads();

    // --- this thread's pair range ---
    const int E = e2 >> 1;
    int k = blockIdx.x * W + 2 * t;            // even: first edge of the pair
    const int kend = min(blockIdx.x * W + W, E);
    if (k >= kend) return;

    int lo = 0, hi = NG;
    #pragma unroll
    for (int step = 0; step < 8; ++step) {
        const int mid = (lo + hi) >> 1;
        if (k >= s_ie[mid]) lo = mid; else hi = mid;
    }
    int g = lo;
    int e_hi = s_ie[g + 1];

    int4v* out4 = reinterpret_cast<int4v*>(d_out);
    for (; k < kend; k += 512) {               // 256 threads x 2 edges
        while (k >= e_hi) { ++g; e_hi = s_ie[g + 1]; }
        const int base = s_in[g];
        const int deg = (s_in[g + 1] - base) - 1;   // >= 1 where edges exist
        const int kl = k - s_ie[g];
        int i = (int)((float)kl * __builtin_amdgcn_rcpf((float)deg));
        int r = kl - i * deg;
        if (r < 0)         { --i; r += deg; }
        else if (r >= deg) { ++i; r -= deg; }
        const int j1 = r + ((r >= i) ? 1 : 0);
        int i2 = i, r2 = r + 1;
        if (r2 == deg) { r2 = 0; ++i2; }            // wrap to next row
        const int j2 = r2 + ((r2 >= i2) ? 1 : 0);
        int4v v;
        v.x = base + i;  v.y = base + j1;
        v.z = base + i2; v.w = base + j2;
        __builtin_nontemporal_store(v, &out4[k >> 1]);
    }
}

extern "C" void kernel_launch(void* const* d_in, const int* in_sizes, int n_in,
                              void* d_out, int out_size, void* d_ws, size_t ws_size,
                              hipStream_t stream) {
    const int* num_nodes = (const int*)d_in[0];  // [256] int32
    int* out = (int*)d_out;                      // [2E + 256] int32
    const int e2 = out_size - NG;                // 2*E
    const int E = e2 / 2;                        // E is even (sum of n*(n-1))

    // Edges per block: uniform, rounded to 128 edges (pair- and wave-aligned).
    int W = (E + NBLK - 1) / NBLK;
    W = (W + 127) & ~127;

    fc_pair_kernel<<<NBLK, 256, 0, stream>>>(num_nodes, out, e2, W);
}